// Round 3
// baseline (993.439 us; speedup 1.0000x reference)
//
#include <hip/hip_runtime.h>
#include <hip/hip_bf16.h>

// bf16 MFMA fragment types (per cdna_hip_programming.md §3, compile-verified on gfx950)
typedef __attribute__((ext_vector_type(8))) short bf16x8;
typedef __attribute__((ext_vector_type(4))) float floatx4;
typedef __attribute__((ext_vector_type(4))) short short4v;

__device__ inline short f2bf(float f) {
  union { float f; unsigned u; } v; v.f = f;
  unsigned r = v.u + 0x7fffu + ((v.u >> 16) & 1u);  // round-to-nearest-even
  return (short)(r >> 16);
}

// async global->LDS, 16B per lane. LDS dest semantics: wave-uniform base + lane*16.
__device__ inline void gload_lds16(const short* g, short* l) {
  __builtin_amdgcn_global_load_lds(
      (const __attribute__((address_space(1))) unsigned int*)g,
      (__attribute__((address_space(3))) unsigned int*)l, 16, 0, 0);
}

// ---------------- Kernel 0: fp32 -> bf16 conversion (x and the 3 weight mats)
__global__ __launch_bounds__(256) void cvt_kernel(
    const float* __restrict__ x, const float* __restrict__ wq,
    const float* __restrict__ wk, const float* __restrict__ wv,
    short* __restrict__ Xb, short* __restrict__ Wb) {
  long i4 = (long)(blockIdx.x * 256 + threadIdx.x) * 4;
  const float* src; short* dst; long off;
  if (i4 < 16777216L) {
    src = x; dst = Xb; off = i4;
  } else {
    long j = i4 - 16777216L;
    int mat = (int)(j >> 20);
    src = (mat == 0) ? wq : ((mat == 1) ? wk : wv);
    dst = Wb + ((long)mat << 20);
    off = j & 1048575L;
  }
  float4 v = *(const float4*)(src + off);
  short4v o; o.x = f2bf(v.x); o.y = f2bf(v.y); o.z = f2bf(v.z); o.w = f2bf(v.w);
  *(short4v*)(dst + off) = o;
}

// ---------------- Kernel 1: QKV projection as one NT-GEMM, m97 structure. (unchanged)
__global__ __launch_bounds__(256) void qkv_gemm(
    const short* __restrict__ Xb, const short* __restrict__ Wb,
    const float* __restrict__ bq, const float* __restrict__ bk,
    const float* __restrict__ bv,
    short* __restrict__ Qb, short* __restrict__ Kb, short* __restrict__ Vtb) {
  __shared__ short As[128 * 32];
  __shared__ short Bs[128 * 32];

  const int tid  = threadIdx.x;
  const int wave = tid >> 6, lane = tid & 63;
  const int quad = lane >> 4, l16 = lane & 15;
  const int wm = wave & 1, wn = wave >> 1;

  const int row0 = blockIdx.x * 128;
  const int col0 = blockIdx.y * 128;

  const int srow = wave * 16 + (lane >> 2);
  const int skof = (lane & 3) * 8;
  const short* gA0 = Xb + (size_t)(row0 + srow) * 1024 + skof;
  const short* gA1 = gA0 + (size_t)64 * 1024;
  const short* gB0 = Wb + (size_t)(col0 + srow) * 1024 + skof;
  const short* gB1 = gB0 + (size_t)64 * 1024;
  short* lA0 = As + (wave * 16) * 32 + lane * 8;
  short* lA1 = As + (64 + wave * 16) * 32 + lane * 8;
  short* lB0 = Bs + (wave * 16) * 32 + lane * 8;
  short* lB1 = Bs + (64 + wave * 16) * 32 + lane * 8;

  floatx4 acc[4][4] = {};

  for (int k = 0; k < 1024; k += 32) {
    gload_lds16(gA0 + k, lA0);
    gload_lds16(gA1 + k, lA1);
    gload_lds16(gB0 + k, lB0);
    gload_lds16(gB1 + k, lB1);
    __syncthreads();

    bf16x8 af[4], bfr[4];
#pragma unroll
    for (int mt = 0; mt < 4; mt++)
      af[mt] = *(const bf16x8*)(As + (wm * 64 + mt * 16 + l16) * 32 + quad * 8);
#pragma unroll
    for (int nb = 0; nb < 4; nb++)
      bfr[nb] = *(const bf16x8*)(Bs + (wn * 64 + nb * 16 + l16) * 32 + quad * 8);
#pragma unroll
    for (int mt = 0; mt < 4; mt++)
#pragma unroll
      for (int nb = 0; nb < 4; nb++)
        acc[mt][nb] = __builtin_amdgcn_mfma_f32_16x16x32_bf16(af[mt], bfr[nb], acc[mt][nb], 0, 0, 0);
    __syncthreads();
  }

#pragma unroll
  for (int nb = 0; nb < 4; nb++) {
    const int col = col0 + wn * 64 + nb * 16 + l16;
    const int mat = col >> 10;
    const int cn  = col & 1023;
    const float* bias = (mat == 0) ? bq : (mat == 1) ? bk : bv;
    const float bb = bias[cn];
    const float qs = (mat == 0) ? 0.03125f : 1.0f;
#pragma unroll
    for (int mt = 0; mt < 4; mt++) {
#pragma unroll
      for (int r = 0; r < 4; r++) {
        const int row = row0 + wm * 64 + mt * 16 + quad * 4 + r;
        short o = f2bf((acc[mt][nb][r] + bb) * qs);
        if (mat == 0)      Qb[(size_t)row * 1024 + cn] = o;
        else if (mat == 1) Kb[(size_t)row * 1024 + cn] = o;
        else {
          int bat = row >> 11, t = row & 2047;
          Vtb[((size_t)bat << 21) + (size_t)cn * 2048 + t] = o;
        }
      }
    }
  }
}

// ---------------- Kernel 2: flash attention, causal. Block = 256 thr (4 waves).
// Q-tile = 16 rows, KV-tile = 64. Wave w: S-tile cols [w*16,w*16+16); PV cols [w*256,w*256+256).
// Softmax: in-register per-thread m/l state, shuffle reductions (row = contiguous 16 lanes).
// 2 barriers per k-tile.
__global__ __launch_bounds__(256) void flash_attn(
    const short* __restrict__ Qb, const short* __restrict__ Kb,
    const short* __restrict__ Vtb, float* __restrict__ out) {
  __shared__ float Sf[16][66];
  __shared__ short Pb[16][72];
  __shared__ float arow[16];
  __shared__ float lrow[16];

  const int b  = blockIdx.x & 7;
  const int qt = 127 - (blockIdx.x >> 3);  // heavy (late) q-tiles first
  const int qbase = qt * 16;
  const int tid = threadIdx.x;
  const int wave = tid >> 6, lane = tid & 63;
  const int quad = lane >> 4, l16 = lane & 15;

  const short* Qp = Qb + ((size_t)b << 21);
  const short* Kp = Kb + ((size_t)b << 21);
  const short* Vp = Vtb + ((size_t)b << 21);

  floatx4 O[16] = {};

  const short* qptr  = Qp + (size_t)(qbase + l16) * 1024 + quad * 8;
  const short* kptr0 = Kp + (size_t)(wave * 16 + l16) * 1024 + quad * 8;

  const int row = tid >> 4, sub = tid & 15;  // softmax ownership: row's 16 thr in ONE wave
  const int gr = qbase + row;
  const int ntiles = (qt >> 2) + 1;
  const int vc0 = wave * 256;

  float m_i = -1e30f, l_i = 0.0f;

  for (int kt = 0; kt < ntiles; kt++) {
    const int kvbase = kt * 64;
    // ---- S = (Q/32) K^T : wave -> one 16x16 tile; 4 independent acc chains over d
    floatx4 s0 = {}, s1 = {}, s2 = {}, s3 = {};
    const short* kptr = kptr0 + (size_t)kvbase * 1024;
#pragma unroll 2
    for (int d = 0; d < 1024; d += 128) {
      bf16x8 qa0 = *(const bf16x8*)(qptr + d);
      bf16x8 kb0 = *(const bf16x8*)(kptr + d);
      bf16x8 qa1 = *(const bf16x8*)(qptr + d + 32);
      bf16x8 kb1 = *(const bf16x8*)(kptr + d + 32);
      bf16x8 qa2 = *(const bf16x8*)(qptr + d + 64);
      bf16x8 kb2 = *(const bf16x8*)(kptr + d + 64);
      bf16x8 qa3 = *(const bf16x8*)(qptr + d + 96);
      bf16x8 kb3 = *(const bf16x8*)(kptr + d + 96);
      s0 = __builtin_amdgcn_mfma_f32_16x16x32_bf16(qa0, kb0, s0, 0, 0, 0);
      s1 = __builtin_amdgcn_mfma_f32_16x16x32_bf16(qa1, kb1, s1, 0, 0, 0);
      s2 = __builtin_amdgcn_mfma_f32_16x16x32_bf16(qa2, kb2, s2, 0, 0, 0);
      s3 = __builtin_amdgcn_mfma_f32_16x16x32_bf16(qa3, kb3, s3, 0, 0, 0);
    }
    floatx4 s4 = (s0 + s1) + (s2 + s3);
#pragma unroll
    for (int r = 0; r < 4; r++)
      Sf[quad * 4 + r][wave * 16 + l16] = s4[r];
    __syncthreads();  // B0: S complete (also: everyone done reading Pb/arow of prev iter)

    // ---- online softmax, register state + shuffle reduce over the row's 16 lanes
    float sv[4], mx = -1e30f;
#pragma unroll
    for (int j = 0; j < 4; j++) {
      const int c = sub * 4 + j;
      float v = Sf[row][c];
      if (kvbase + c > gr) v = -1e30f;  // causal mask
      sv[j] = v;
      mx = fmaxf(mx, v);
    }
#pragma unroll
    for (int msk = 1; msk <= 8; msk <<= 1)
      mx = fmaxf(mx, __shfl_xor(mx, msk, 64));
    const float mn = fmaxf(m_i, mx);
    const float alpha = __expf(m_i - mn);
    m_i = mn;
    float ps = 0.0f;
#pragma unroll
    for (int j = 0; j < 4; j++) {
      float p = __expf(sv[j] - mn);
      ps += p;
      Pb[row][sub * 4 + j] = f2bf(p);
    }
#pragma unroll
    for (int msk = 1; msk <= 8; msk <<= 1)
      ps += __shfl_xor(ps, msk, 64);
    l_i = l_i * alpha + ps;
    if (sub == 0) arow[row] = alpha;
    __syncthreads();  // B1: Pb + arow ready

    // ---- O = diag(alpha) O + P V  (wave owns 256 V columns; V pre-transposed)
    float al[4];
#pragma unroll
    for (int r = 0; r < 4; r++) al[r] = arow[quad * 4 + r];
#pragma unroll
    for (int nb = 0; nb < 16; nb++)
#pragma unroll
      for (int r = 0; r < 4; r++) O[nb][r] *= al[r];

#pragma unroll
    for (int kc = 0; kc < 2; kc++) {
      bf16x8 pa = *(const bf16x8*)&Pb[l16][kc * 32 + quad * 8];
#pragma unroll
      for (int nb = 0; nb < 16; nb++) {
        const short* vptr = Vp + (size_t)(vc0 + nb * 16 + l16) * 2048 + kvbase + kc * 32 + quad * 8;
        bf16x8 vb = *(const bf16x8*)vptr;
        O[nb] = __builtin_amdgcn_mfma_f32_16x16x32_bf16(pa, vb, O[nb], 0, 0, 0);
      }
    }
  }

  if (sub == 0) lrow[row] = 1.0f / l_i;
  __syncthreads();
  float linv[4];
#pragma unroll
  for (int r = 0; r < 4; r++) linv[r] = lrow[quad * 4 + r];
#pragma unroll
  for (int nb = 0; nb < 16; nb++)
#pragma unroll
    for (int r = 0; r < 4; r++) {
      const int rr = qbase + quad * 4 + r;
      const int cc = vc0 + nb * 16 + l16;
      out[((size_t)b * 2048 + rr) * 1024 + cc] = O[nb][r] * linv[r];
    }
}

extern "C" void kernel_launch(void* const* d_in, const int* in_sizes, int n_in,
                              void* d_out, int out_size, void* d_ws, size_t ws_size,
                              hipStream_t stream) {
  const float* x  = (const float*)d_in[0];
  const float* Wq = (const float*)d_in[1];
  const float* bq = (const float*)d_in[2];
  const float* Wk = (const float*)d_in[3];
  const float* bk = (const float*)d_in[4];
  const float* Wv = (const float*)d_in[5];
  const float* bv = (const float*)d_in[6];
  float* out = (float*)d_out;

  char* ws = (char*)d_ws;
  short* Xb  = (short*)(ws);                 // 16384x1024 bf16 = 33,554,432 B
  short* Wb  = (short*)(ws + 33554432);      // 3x1024x1024 bf16 = 6,291,456 B (Wq|Wk|Wv rows)
  short* Qb  = (short*)(ws + 39845888);      // 33,554,432 B (pre-scaled by 1/32)
  short* Kb  = (short*)(ws + 73400320);      // 33,554,432 B
  short* Vtb = (short*)(ws + 106954752);     // 33,554,432 B (per-batch transposed [C][T])

  // 0) convert x + weights to bf16
  cvt_kernel<<<19456, 256, 0, stream>>>(x, Wq, Wk, Wv, Xb, Wb);
  // 1) QKV projection: one 16384x3072x1024 NT-GEMM
  qkv_gemm<<<dim3(128, 24), 256, 0, stream>>>(Xb, Wb, bq, bk, bv, Qb, Kb, Vtb);
  // 2) flash attention: 8 batches x 128 q-tiles, heavy tiles first
  flash_attn<<<1024, 256, 0, stream>>>(Qb, Kb, Vtb, out);
}

// Round 4
// 673.277 us; speedup vs baseline: 1.4755x; 1.4755x over previous
//
#include <hip/hip_runtime.h>
#include <hip/hip_bf16.h>

typedef __attribute__((ext_vector_type(8))) short bf16x8;
typedef __attribute__((ext_vector_type(4))) float floatx4;
typedef __attribute__((ext_vector_type(4))) short short4v;

__device__ inline short f2bf(float f) {
  union { float f; unsigned u; } v; v.f = f;
  unsigned r = v.u + 0x7fffu + ((v.u >> 16) & 1u);  // round-to-nearest-even
  return (short)(r >> 16);
}

__device__ inline void gload_lds16(const short* g, short* l) {
  __builtin_amdgcn_global_load_lds(
      (const __attribute__((address_space(1))) unsigned int*)g,
      (__attribute__((address_space(3))) unsigned int*)l, 16, 0, 0);
}

// ---------------- Kernel 0: fp32 -> bf16 conversion (x and the 3 weight mats)
__global__ __launch_bounds__(256) void cvt_kernel(
    const float* __restrict__ x, const float* __restrict__ wq,
    const float* __restrict__ wk, const float* __restrict__ wv,
    short* __restrict__ Xb, short* __restrict__ Wb) {
  long i4 = (long)(blockIdx.x * 256 + threadIdx.x) * 4;
  const float* src; short* dst; long off;
  if (i4 < 16777216L) {
    src = x; dst = Xb; off = i4;
  } else {
    long j = i4 - 16777216L;
    int mat = (int)(j >> 20);
    src = (mat == 0) ? wq : ((mat == 1) ? wk : wv);
    dst = Wb + ((long)mat << 20);
    off = j & 1048575L;
  }
  float4 v = *(const float4*)(src + off);
  short4v o; o.x = f2bf(v.x); o.y = f2bf(v.y); o.z = f2bf(v.z); o.w = f2bf(v.w);
  *(short4v*)(dst + off) = o;
}

// ---------------- Kernel 1: QKV NT-GEMM (m97 structure), epilogue writes
// Q/K/V in MFMA-FRAGMENT-LINEAR layouts so flash_attn's loads are lane*8-coalesced:
//  Qf/Kf: [b][t16 (t>>4)][dc (d>>5)][lane=((d>>3)&3)*16 + (t&15)][j=d&7]
//  Vf   : [b][c16 (c>>4)][kc (t>>5)][lane=((t>>3)&3)*16 + (c&15)][j=t&7]
__global__ __launch_bounds__(256) void qkv_gemm(
    const short* __restrict__ Xb, const short* __restrict__ Wb,
    const float* __restrict__ bq, const float* __restrict__ bk,
    const float* __restrict__ bv,
    short* __restrict__ Qf, short* __restrict__ Kf, short* __restrict__ Vf) {
  __shared__ short As[128 * 32];
  __shared__ short Bs[128 * 32];

  const int tid  = threadIdx.x;
  const int wave = tid >> 6, lane = tid & 63;
  const int quad = lane >> 4, l16 = lane & 15;
  const int wm = wave & 1, wn = wave >> 1;

  const int row0 = blockIdx.x * 128;
  const int col0 = blockIdx.y * 128;

  const int srow = wave * 16 + (lane >> 2);
  const int skof = (lane & 3) * 8;
  const short* gA0 = Xb + (size_t)(row0 + srow) * 1024 + skof;
  const short* gA1 = gA0 + (size_t)64 * 1024;
  const short* gB0 = Wb + (size_t)(col0 + srow) * 1024 + skof;
  const short* gB1 = gB0 + (size_t)64 * 1024;
  short* lA0 = As + (wave * 16) * 32 + lane * 8;
  short* lA1 = As + (64 + wave * 16) * 32 + lane * 8;
  short* lB0 = Bs + (wave * 16) * 32 + lane * 8;
  short* lB1 = Bs + (64 + wave * 16) * 32 + lane * 8;

  floatx4 acc[4][4] = {};

  for (int k = 0; k < 1024; k += 32) {
    gload_lds16(gA0 + k, lA0);
    gload_lds16(gA1 + k, lA1);
    gload_lds16(gB0 + k, lB0);
    gload_lds16(gB1 + k, lB1);
    __syncthreads();

    bf16x8 af[4], bfr[4];
#pragma unroll
    for (int mt = 0; mt < 4; mt++)
      af[mt] = *(const bf16x8*)(As + (wm * 64 + mt * 16 + l16) * 32 + quad * 8);
#pragma unroll
    for (int nb = 0; nb < 4; nb++)
      bfr[nb] = *(const bf16x8*)(Bs + (wn * 64 + nb * 16 + l16) * 32 + quad * 8);
#pragma unroll
    for (int mt = 0; mt < 4; mt++)
#pragma unroll
      for (int nb = 0; nb < 4; nb++)
        acc[mt][nb] = __builtin_amdgcn_mfma_f32_16x16x32_bf16(af[mt], bfr[nb], acc[mt][nb], 0, 0, 0);
    __syncthreads();
  }

#pragma unroll
  for (int nb = 0; nb < 4; nb++) {
    const int col = col0 + wn * 64 + nb * 16 + l16;
    const int mat = col >> 10;
    const int cn  = col & 1023;
    const float* bias = (mat == 0) ? bq : (mat == 1) ? bk : bv;
    const float bb = bias[cn];
    const float qs = (mat == 0) ? 0.03125f : 1.0f;  // fold 1/sqrt(C) into Q
#pragma unroll
    for (int mt = 0; mt < 4; mt++) {
#pragma unroll
      for (int r = 0; r < 4; r++) {
        const int row = row0 + wm * 64 + mt * 16 + quad * 4 + r;
        short o = f2bf((acc[mt][nb][r] + bb) * qs);
        const int bat = row >> 11, t = row & 2047;
        if (mat <= 1) {
          // Q/K fragment-linear: m = t, k = cn(=d)
          const size_t idx = ((((size_t)bat * 128 + (t >> 4)) * 32 + (cn >> 5)) << 9)
                           + ((((cn >> 3) & 3) * 16 + (t & 15)) << 3) + (cn & 7);
          if (mat == 0) Qf[idx] = o; else Kf[idx] = o;
        } else {
          // V fragment-linear (PV B-operand): n = cn(=c), k = t(=kv)
          const size_t idx = ((((size_t)bat * 64 + (cn >> 4)) * 64 + (t >> 5)) << 9)
                           + ((((t >> 3) & 3) * 16 + (cn & 15)) << 3) + (t & 7);
          Vf[idx] = o;
        }
      }
    }
  }
}

// ---------------- Kernel 2: flash attention, causal. Block = 256 thr (4 waves).
// Q-tile = 16 rows, KV-tile = 64. QK^T: wave w owns d in [w*256, w*256+256) — its Q
// fragments (8 x bf16x8 = 32 VGPR) loaded ONCE; partial S summed across waves in LDS.
// PV: wave w owns V cols [w*256, w*256+256). All global loads are lane*8-coalesced
// fragment-linear loads. 2 barriers / k-tile.
__global__ __launch_bounds__(256) void flash_attn(
    const short* __restrict__ Qf, const short* __restrict__ Kf,
    const short* __restrict__ Vf, float* __restrict__ out) {
  __shared__ float Sf[4][16][64];
  __shared__ short Pb[16][72];
  __shared__ float arow[16];
  __shared__ float lrow[16];

  const int b  = blockIdx.x & 7;
  const int qt = 127 - (blockIdx.x >> 3);  // heavy (late) q-tiles first
  const int tid = threadIdx.x;
  const int wave = tid >> 6, lane = tid & 63;
  const int quad = lane >> 4, l16 = lane & 15;

  // Q fragments for this wave's d-range, loaded once (coalesced)
  const short* qp = Qf + ((((size_t)b * 128 + qt) * 32 + wave * 8) << 9) + lane * 8;
  bf16x8 qfr[8];
#pragma unroll
  for (int dc = 0; dc < 8; dc++)
    qfr[dc] = *(const bf16x8*)(qp + (dc << 9));

  const int row = tid >> 4, sub = tid & 15;  // softmax: row's 16 threads in ONE wave
  const int gr = qt * 16 + row;
  const int ntiles = (qt >> 2) + 1;

  floatx4 O[16] = {};
  float m_i = -1e30f, l_i = 0.0f;

  for (int kt = 0; kt < ntiles; kt++) {
    // ---- partial S over this wave's 256 d's, all 64 kv cols (4 indep chains)
    const short* kp = Kf + ((((size_t)b * 128 + kt * 4) * 32 + wave * 8) << 9) + lane * 8;
    floatx4 s[4] = {};
#pragma unroll
    for (int nt = 0; nt < 4; nt++)
#pragma unroll
      for (int dc = 0; dc < 8; dc++) {
        bf16x8 kb = *(const bf16x8*)(kp + ((nt * 32 + dc) << 9));
        s[nt] = __builtin_amdgcn_mfma_f32_16x16x32_bf16(qfr[dc], kb, s[nt], 0, 0, 0);
      }
#pragma unroll
    for (int nt = 0; nt < 4; nt++)
#pragma unroll
      for (int r = 0; r < 4; r++)
        Sf[wave][quad * 4 + r][nt * 16 + l16] = s[nt][r];
    __syncthreads();  // B0: all partials in LDS

    // ---- online softmax (sum partials, register m/l, shuffle reduce over 16 lanes)
    const int kvbase = kt * 64;
    float sv[4], mx = -1e30f;
#pragma unroll
    for (int j = 0; j < 4; j++) {
      const int c = sub * 4 + j;
      float v = Sf[0][row][c] + Sf[1][row][c] + Sf[2][row][c] + Sf[3][row][c];
      if (kvbase + c > gr) v = -1e30f;  // causal mask
      sv[j] = v;
      mx = fmaxf(mx, v);
    }
#pragma unroll
    for (int msk = 1; msk <= 8; msk <<= 1)
      mx = fmaxf(mx, __shfl_xor(mx, msk, 64));
    const float mn = fmaxf(m_i, mx);
    const float alpha = __expf(m_i - mn);
    m_i = mn;
    float ps = 0.0f;
#pragma unroll
    for (int j = 0; j < 4; j++) {
      float p = __expf(sv[j] - mn);
      ps += p;
      Pb[row][sub * 4 + j] = f2bf(p);
    }
#pragma unroll
    for (int msk = 1; msk <= 8; msk <<= 1)
      ps += __shfl_xor(ps, msk, 64);
    l_i = l_i * alpha + ps;
    if (sub == 0) arow[row] = alpha;
    __syncthreads();  // B1: Pb + arow ready

    // ---- O = diag(alpha) O + P V   (wave owns 256 V cols; coalesced V frags)
    float al[4];
#pragma unroll
    for (int r = 0; r < 4; r++) al[r] = arow[quad * 4 + r];
#pragma unroll
    for (int nb = 0; nb < 16; nb++)
#pragma unroll
      for (int r = 0; r < 4; r++) O[nb][r] *= al[r];

    const short* vp = Vf + ((((size_t)b * 64 + wave * 16) * 64 + kt * 2) << 9) + lane * 8;
#pragma unroll
    for (int kc = 0; kc < 2; kc++) {
      bf16x8 pa = *(const bf16x8*)&Pb[l16][kc * 32 + quad * 8];
#pragma unroll
      for (int nb = 0; nb < 16; nb++) {
        bf16x8 vb = *(const bf16x8*)(vp + (((size_t)nb * 64 + kc) << 9));
        O[nb] = __builtin_amdgcn_mfma_f32_16x16x32_bf16(pa, vb, O[nb], 0, 0, 0);
      }
    }
  }

  if (sub == 0) lrow[row] = 1.0f / l_i;
  __syncthreads();
  float linv[4];
#pragma unroll
  for (int r = 0; r < 4; r++) linv[r] = lrow[quad * 4 + r];
#pragma unroll
  for (int nb = 0; nb < 16; nb++)
#pragma unroll
    for (int r = 0; r < 4; r++) {
      const int rr = qt * 16 + quad * 4 + r;
      const int cc = wave * 256 + nb * 16 + l16;
      out[((size_t)b * 2048 + rr) * 1024 + cc] = O[nb][r] * linv[r];
    }
}

extern "C" void kernel_launch(void* const* d_in, const int* in_sizes, int n_in,
                              void* d_out, int out_size, void* d_ws, size_t ws_size,
                              hipStream_t stream) {
  const float* x  = (const float*)d_in[0];
  const float* Wq = (const float*)d_in[1];
  const float* bq = (const float*)d_in[2];
  const float* Wk = (const float*)d_in[3];
  const float* bk = (const float*)d_in[4];
  const float* Wv = (const float*)d_in[5];
  const float* bv = (const float*)d_in[6];
  float* out = (float*)d_out;

  char* ws = (char*)d_ws;
  short* Xb = (short*)(ws);                 // 16384x1024 bf16 = 33,554,432 B
  short* Wb = (short*)(ws + 33554432);      // 3x1024x1024 bf16 = 6,291,456 B
  short* Qf = (short*)(ws + 39845888);      // 33,554,432 B fragment-linear (pre-scaled 1/32)
  short* Kf = (short*)(ws + 73400320);      // 33,554,432 B fragment-linear
  short* Vf = (short*)(ws + 106954752);     // 33,554,432 B fragment-linear

  cvt_kernel<<<19456, 256, 0, stream>>>(x, Wq, Wk, Wv, Xb, Wb);
  qkv_gemm<<<dim3(128, 24), 256, 0, stream>>>(Xb, Wb, bq, bk, bv, Qf, Kf, Vf);
  flash_attn<<<1024, 256, 0, stream>>>(Qf, Kf, Vf, out);
}